// Round 6
// baseline (676.318 us; speedup 1.0000x reference)
//
#include <hip/hip_runtime.h>
#include <stdint.h>

#define ALPHA_ 0.7f
constexpr int Tn = 256, Vn = 256, Qn = 32, Fn = 64, Dn = 512;
constexpr int Mn = Tn * Qn;   // 8192
constexpr int Nn = Vn * Fn;   // 16384
constexpr int Kn = Dn;        // 512
constexpr int NOT = 8;        // N-otiles per block
constexpr int GT  = (Kn / 64) * NOT;  // 64 flat K-steps per block

typedef float  f32x4  __attribute__((ext_vector_type(4)));
typedef __bf16 bf16x8 __attribute__((ext_vector_type(8)));

static __device__ __forceinline__ unsigned short f2bf(float f) {
  uint32_t x = __builtin_bit_cast(uint32_t, f);
  x += 0x7fffu + ((x >> 16) & 1u);   // round-to-nearest-even
  return (unsigned short)(x >> 16);
}

static __device__ __forceinline__ void gload_lds16(const void* g, void* l) {
  __builtin_amdgcn_global_load_lds(
      (const __attribute__((address_space(1))) uint32_t*)g,
      (__attribute__((address_space(3))) uint32_t*)l, 16, 0, 0);
}

#define BAR()   asm volatile("s_barrier" ::: "memory")
#define SBAR()  __builtin_amdgcn_sched_barrier(0)
#define LGKM(N) do { asm volatile("s_waitcnt lgkmcnt(" #N ")" ::: "memory"); \
                     SBAR(); } while (0)
#define VMW(N)  do { asm volatile("s_waitcnt vmcnt(" #N ")" ::: "memory"); \
                     SBAR(); } while (0)

// ---- kernel 1/2: L2-normalize rows of [R][512] f32 -> bf16 ----
__global__ void normalize_rows(const float* __restrict__ src,
                               uint4* __restrict__ dst) {
  const int wave = threadIdx.x >> 6;
  const int lane = threadIdx.x & 63;
  const int row  = blockIdx.x * 4 + wave;
  const float4* p = reinterpret_cast<const float4*>(src + (size_t)row * Dn + lane * 8);
  float4 x0 = p[0];
  float4 x1 = p[1];
  float ss = x0.x*x0.x + x0.y*x0.y + x0.z*x0.z + x0.w*x0.w
           + x1.x*x1.x + x1.y*x1.y + x1.z*x1.z + x1.w*x1.w;
  #pragma unroll
  for (int m = 1; m < 64; m <<= 1) ss += __shfl_xor(ss, m, 64);
  const float inv = 1.0f / fmaxf(sqrtf(ss), 1e-12f);
  union { unsigned short u[8]; uint4 v; } pk;
  const float f[8] = {x0.x, x0.y, x0.z, x0.w, x1.x, x1.y, x1.z, x1.w};
  #pragma unroll
  for (int j = 0; j < 8; ++j) pk.u[j] = f2bf(f[j] * inv);
  dst[(size_t)row * (Dn / 8) + lane] = pk.v;
}

// ---- fused MaxSim GEMM: persistent 256x256 tiles, reg-double-buffered ----
// 256 blocks, 1/CU; block sweeps 8 N-tiles (64 flat K-steps).
// Frag double-buffer: af (A0 cur), af2 (A1 cur), bqA/bqB (B alternating).
// Per tile: P_A{issue A1 reads; lgkm(8); MFMA H0 (A1 drains under); lgkm(0)}
//           P_B{vm0; BAR; issue next-tile A0+B reads; stage g+2; MFMA H1
//               (reads+stages drain under); epilogue every 8th}.
// One barrier per K-tile. Reads of a buffer always complete (lgkm) before
// the BAR that precedes its restage; cross-buffer reads always follow
// vm0+BAR so all waves' stages have landed.
__global__ __launch_bounds__(512, 2)
void maxsim256_kernel(const uint16_t* __restrict__ Abf,
                      const uint16_t* __restrict__ Bbf,
                      const float* __restrict__ text,
                      const float* __restrict__ clip,
                      const float* __restrict__ logit_scale,
                      float* __restrict__ out) {
  __shared__ __align__(16) unsigned char lds[131072];
  const int tid  = threadIdx.x;
  const int lane = tid & 63;
  const int wave = tid >> 6;    // 0..7
  const int wr   = wave >> 2;   // 0..1 -> rows [wr*128, +128)
  const int wc   = wave & 3;    // 0..3 -> cols [wc*64, +64)
  const int bid  = blockIdx.x;  // 0..255
  const int nx0  = (bid & 7) * 8;   // first N-tile of this block's chunk
  const int by   = bid >> 3;        // M-tile 0..31

  const float scale = fminf(expf(logit_scale[0]), 100.0f);
  const float coefG = ALPHA_ * scale;
  const float coefL = (1.0f - ALPHA_) * scale * (1.0f / (float)Qn);

  const char* Ag  = reinterpret_cast<const char*>(Abf) + (size_t)by  * 262144;
  const char* Bg0 = reinterpret_cast<const char*>(Bbf) + (size_t)nx0 * 262144;

  // per-thread staging source offsets (j = 0,1)
  unsigned srcA[2], srcB[2], ldsoff[2];
  #pragma unroll
  for (int j = 0; j < 2; ++j) {
    const unsigned r = (j * 8 + wave) * 8 + (lane >> 3);
    const unsigned c = (((lane & 7) ^ (lane >> 3)) << 4);
    srcA[j]  = (((r >> 6) << 7) + (r & 63)) * 1024 + c;  // + h*65536 + kt*128
    srcB[j]  = (((r >> 5) << 6) + (r & 31)) * 1024 + c;  // + h*32768 + kt*128
    ldsoff[j] = (j * 8 + wave) * 1024;
  }

  auto stage = [&](int buf, int isB, int h, int g) {
    const unsigned base = buf * 65536 + isB * 32768 + h * 16384;
    const unsigned kt = (g & 7) * 128;
    #pragma unroll
    for (int j = 0; j < 2; ++j) {
      const void* src = isB
          ? (const void*)(Bg0 + (size_t)((g >> 3) * 262144 + h * 32768 + kt + srcB[j]))
          : (const void*)(Ag  + (size_t)(h * 65536 + kt + srcA[j]));
      gload_lds16(src, &lds[base + ldsoff[j]]);
    }
  };
  auto stage_tile = [&](int buf, int g) {   // full next-next tile: 8 loads
    stage(buf, 0, 0, g); stage(buf, 0, 1, g);
    stage(buf, 1, 0, g); stage(buf, 1, 1, g);
  };

  f32x4 acc[8][4];
  #pragma unroll
  for (int i = 0; i < 8; ++i)
    #pragma unroll
    for (int j = 0; j < 4; ++j)
      acc[i][j] = {0.f, 0.f, 0.f, 0.f};

  bf16x8 af[4][2];    // A half-0 of current tile
  bf16x8 af2[4][2];   // A half-1 of current tile
  bf16x8 bqA[4][2];   // B frags, even tiles
  bf16x8 bqB[4][2];   // B frags, odd tiles

  const int rA  = lane & 15;
  const int kg  = lane >> 4;
  const unsigned key = (unsigned)(rA & 7) << 4;

  auto ldA_into = [&](int buf, int h, bf16x8 (&dst)[4][2]) {   // 8 x b128
    const unsigned b = buf * 65536 + h * 16384;
    #pragma unroll
    for (int m = 0; m < 4; ++m) {
      const unsigned s = (unsigned)(wr * 64 + m * 16 + rA);
      #pragma unroll
      for (int kk = 0; kk < 2; ++kk) {
        const unsigned kb = kk * 64 + kg * 16;
        dst[m][kk] = *reinterpret_cast<const bf16x8*>(&lds[b + s * 128 + (kb ^ key)]);
      }
    }
  };
  auto ldB_into = [&](int buf, bf16x8 (&dst)[4][2]) {          // 8 x b128
    #pragma unroll
    for (int h = 0; h < 2; ++h) {
      const unsigned b = buf * 65536 + 32768 + h * 16384;
      #pragma unroll
      for (int n = 0; n < 2; ++n) {
        const unsigned s = (unsigned)(wc * 32 + n * 16 + rA);
        #pragma unroll
        for (int kk = 0; kk < 2; ++kk) {
          const unsigned kb = kk * 64 + kg * 16;
          dst[h * 2 + n][kk] = *reinterpret_cast<const bf16x8*>(&lds[b + s * 128 + (kb ^ key)]);
        }
      }
    }
  };
  auto mfma_cluster = [&](int hm, bf16x8 (&a)[4][2], bf16x8 (&b)[4][2]) {
    __builtin_amdgcn_s_setprio(1);          // 32 MFMA: full K=64 x quadrant row
    #pragma unroll
    for (int m = 0; m < 4; ++m)
      #pragma unroll
      for (int ni = 0; ni < 4; ++ni)
        #pragma unroll
        for (int kk = 0; kk < 2; ++kk)
          acc[hm * 4 + m][ni] = __builtin_amdgcn_mfma_f32_16x16x32_bf16(
              a[m][kk], b[ni][kk], acc[hm * 4 + m][ni], 0, 0, 0);
    __builtin_amdgcn_s_setprio(0);
  };

  // per-otile epilogue. C/D: col=lane&15, row=(lane>>4)*4+reg  [m89-verified]
  auto epilogue = [&](int ot) {
    const int v_out = (nx0 + ot) * 4 + wc;
    const float4* cp = reinterpret_cast<const float4*>(clip + (size_t)v_out * Dn) + lane * 2;
    const float4 c0 = cp[0], c1 = cp[1];
    #pragma unroll
    for (int gq = 0; gq < 4; ++gq) {
      float sum = 0.f;
      #pragma unroll
      for (int m2 = 0; m2 < 2; ++m2) {
        const int mi = gq * 2 + m2;
        #pragma unroll
        for (int reg = 0; reg < 4; ++reg) {
          float rm = fmaxf(fmaxf(acc[mi][0][reg], acc[mi][1][reg]),
                           fmaxf(acc[mi][2][reg], acc[mi][3][reg]));
          rm = fmaxf(rm, __shfl_xor(rm, 1, 64));
          rm = fmaxf(rm, __shfl_xor(rm, 2, 64));
          rm = fmaxf(rm, __shfl_xor(rm, 4, 64));
          rm = fmaxf(rm, __shfl_xor(rm, 8, 64));   // max over all 64 f-cols
          sum += rm;
        }
      }
      sum += __shfl_xor(sum, 16, 64);
      sum += __shfl_xor(sum, 32, 64);              // sum over 32 q-rows
      const float4* tp = reinterpret_cast<const float4*>(
          text + (size_t)(by * 8 + wr * 4 + gq) * Dn) + lane * 2;
      const float4 t0 = tp[0], t1 = tp[1];
      float gd = t0.x*c0.x + t0.y*c0.y + t0.z*c0.z + t0.w*c0.w
               + t1.x*c1.x + t1.y*c1.y + t1.z*c1.z + t1.w*c1.w;
      gd += __shfl_xor(gd, 1, 64);  gd += __shfl_xor(gd, 2, 64);
      gd += __shfl_xor(gd, 4, 64);  gd += __shfl_xor(gd, 8, 64);
      gd += __shfl_xor(gd, 16, 64); gd += __shfl_xor(gd, 32, 64);
      if (lane == 0)
        out[(by * 8 + wr * 4 + gq) * Vn + v_out] = coefG * gd + coefL * sum;
    }
    #pragma unroll
    for (int i = 0; i < 8; ++i)
      #pragma unroll
      for (int j = 0; j < 4; ++j)
        acc[i][j] = {0.f, 0.f, 0.f, 0.f};
  };

  auto tile_step = [&](int g, int buf, bf16x8 (&bq_cur)[4][2],
                       bf16x8 (&bq_nxt)[4][2]) {
    // P_A: A1 reads fly under H0
    ldA_into(buf, 1, af2);                 // issue 8 reads
    SBAR();
    LGKM(8);                               // 16 older (af, bq_cur) landed
    mfma_cluster(0, af, bq_cur);           // H0: 32 MFMA, A1 drains underneath
    LGKM(0);                               // af2 landed
    // P_B: next-tile reads + restage fly under H1
    VMW(0);                                // own stages for tile g+1 landed
    BAR();                                 // all waves: reads done, stages landed
    if (g + 1 < GT) {
      ldA_into(buf ^ 1, 0, af);            // 8 reads: A0(g+1)
      ldB_into(buf ^ 1, bq_nxt);           // 8 reads: B(g+1)
      SBAR();
    }
    if (g + 2 < GT) stage_tile(buf, g + 2);  // 8 gload_lds into freed buf
    mfma_cluster(1, af2, bq_cur);          // H1: 32 MFMA, reads+stages drain
    if ((g & 7) == 7) epilogue(g >> 3);    // otile done
  };

  // prologue: stage tile0+tile1, land tile0, preload its frags
  stage_tile(0, 0);
  stage_tile(1, 1);
  VMW(8);                                  // tile0 landed
  BAR();
  ldA_into(0, 0, af);
  ldB_into(0, bqA);
  SBAR();

  for (int t = 0; t < GT; t += 2) {
    tile_step(t,     0, bqA, bqB);
    tile_step(t + 1, 1, bqB, bqA);
  }
}

extern "C" void kernel_launch(void* const* d_in, const int* in_sizes, int n_in,
                              void* d_out, int out_size, void* d_ws, size_t ws_size,
                              hipStream_t stream) {
  const float* text        = (const float*)d_in[0];
  const float* clip        = (const float*)d_in[1];
  const float* concept     = (const float*)d_in[2];
  const float* frames      = (const float*)d_in[3];
  const float* logit_scale = (const float*)d_in[4];
  float* out = (float*)d_out;

  uint16_t* Abf = (uint16_t*)d_ws;              //  8192*512 bf16 = 8 MiB
  uint16_t* Bbf = Abf + (size_t)Mn * Kn;        // 16384*512 bf16 = 16 MiB

  normalize_rows<<<Mn / 4, 256, 0, stream>>>(concept, (uint4*)Abf);
  normalize_rows<<<Nn / 4, 256, 0, stream>>>(frames, (uint4*)Bbf);
  maxsim256_kernel<<<256, 512, 0, stream>>>(Abf, Bbf, text, clip, logit_scale, out);
}

// Round 7
// 302.769 us; speedup vs baseline: 2.2338x; 2.2338x over previous
//
#include <hip/hip_runtime.h>
#include <stdint.h>

#define ALPHA_ 0.7f
constexpr int Tn = 256, Vn = 256, Qn = 32, Fn = 64, Dn = 512;
constexpr int Mn = Tn * Qn;   // 8192
constexpr int Nn = Vn * Fn;   // 16384
constexpr int Kn = Dn;        // 512
constexpr int NOT = 8;        // N-otiles per block
constexpr int GT  = (Kn / 64) * NOT;  // 64 flat K-steps per block

typedef float  f32x4  __attribute__((ext_vector_type(4)));
typedef __bf16 bf16x8 __attribute__((ext_vector_type(8)));

static __device__ __forceinline__ unsigned short f2bf(float f) {
  uint32_t x = __builtin_bit_cast(uint32_t, f);
  x += 0x7fffu + ((x >> 16) & 1u);   // round-to-nearest-even
  return (unsigned short)(x >> 16);
}

static __device__ __forceinline__ void gload_lds16(const void* g, void* l) {
  __builtin_amdgcn_global_load_lds(
      (const __attribute__((address_space(1))) uint32_t*)g,
      (__attribute__((address_space(3))) uint32_t*)l, 16, 0, 0);
}

#define BAR()   asm volatile("s_barrier" ::: "memory")
#define SBAR()  __builtin_amdgcn_sched_barrier(0)
#define LGKM(N) do { asm volatile("s_waitcnt lgkmcnt(" #N ")" ::: "memory"); \
                     SBAR(); } while (0)
#define VMW(N)  do { asm volatile("s_waitcnt vmcnt(" #N ")" ::: "memory"); \
                     SBAR(); } while (0)

// ---- kernel 1/2: L2-normalize rows of [R][512] f32 -> bf16 ----
__global__ void normalize_rows(const float* __restrict__ src,
                               uint4* __restrict__ dst) {
  const int wave = threadIdx.x >> 6;
  const int lane = threadIdx.x & 63;
  const int row  = blockIdx.x * 4 + wave;
  const float4* p = reinterpret_cast<const float4*>(src + (size_t)row * Dn + lane * 8);
  float4 x0 = p[0];
  float4 x1 = p[1];
  float ss = x0.x*x0.x + x0.y*x0.y + x0.z*x0.z + x0.w*x0.w
           + x1.x*x1.x + x1.y*x1.y + x1.z*x1.z + x1.w*x1.w;
  #pragma unroll
  for (int m = 1; m < 64; m <<= 1) ss += __shfl_xor(ss, m, 64);
  const float inv = 1.0f / fmaxf(sqrtf(ss), 1e-12f);
  union { unsigned short u[8]; uint4 v; } pk;
  const float f[8] = {x0.x, x0.y, x0.z, x0.w, x1.x, x1.y, x1.z, x1.w};
  #pragma unroll
  for (int j = 0; j < 8; ++j) pk.u[j] = f2bf(f[j] * inv);
  dst[(size_t)row * (Dn / 8) + lane] = pk.v;
}

// ---- fused MaxSim GEMM: A via LDS (dbuf, swizzled), B direct from L2 ----
// 256 blocks, 1/CU; block sweeps 8 N-tiles (64 flat K-steps), 1 barrier/tile.
// Frags: af=A0(cur) 32, af2=A1(cur) 32, bq=B(cur, in-place rotated) 32 VGPR;
// acc 128 AGPR. Per-wave vm FIFO/tile: [stage A(g+2) x4][B'(g+1) x8] ->
// entering a tile 12 outstanding; VMW(6/4/2/0) before (A0 x bq[ni]) drains
// stage(g+1)+B'[ni] exactly. All waits covered by >=8 MFMAs.
__global__ __launch_bounds__(512, 2)
void maxsim256_kernel(const uint16_t* __restrict__ Abf,
                      const uint16_t* __restrict__ Bbf,
                      const float* __restrict__ text,
                      const float* __restrict__ clip,
                      const float* __restrict__ logit_scale,
                      float* __restrict__ out) {
  __shared__ __align__(16) unsigned char lds[65536];  // 2 bufs x 32KB (A only)
  const int tid  = threadIdx.x;
  const int lane = tid & 63;
  const int wave = tid >> 6;    // 0..7
  const int wr   = wave >> 2;   // 0..1 -> rows [wr*128, +128)
  const int wc   = wave & 3;    // 0..3 -> cols [wc*64, +64)
  const int bid  = blockIdx.x;  // 0..255
  const int nx0  = (bid & 7) * 8;   // first N-otile of this block's chunk
  const int by   = bid >> 3;        // M-tile 0..31

  const float scale = fminf(expf(logit_scale[0]), 100.0f);
  const float coefG = ALPHA_ * scale;
  const float coefL = (1.0f - ALPHA_) * scale * (1.0f / (float)Qn);

  const char* Ag  = reinterpret_cast<const char*>(Abf) + (size_t)by  * 262144;
  const char* Bg0 = reinterpret_cast<const char*>(Bbf) + (size_t)nx0 * 262144;

  // staging source offsets (A only; inverse-permuted + swizzled as r5)
  unsigned srcA[2], ldsoff[2];
  #pragma unroll
  for (int j = 0; j < 2; ++j) {
    const unsigned r = (j * 8 + wave) * 8 + (lane >> 3);
    const unsigned c = (((lane & 7) ^ (lane >> 3)) << 4);
    srcA[j]  = (((r >> 6) << 7) + (r & 63)) * 1024 + c;  // + h*65536 + kt*128
    ldsoff[j] = (j * 8 + wave) * 1024;
  }

  auto stage = [&](int buf, int h, int g) {   // one A-half: 2 gload_lds16
    const unsigned base = buf * 32768 + h * 16384;
    const unsigned kt = (g & 7) * 128;
    #pragma unroll
    for (int j = 0; j < 2; ++j)
      gload_lds16(Ag + (size_t)(h * 65536 + kt + srcA[j]), &lds[base + ldsoff[j]]);
  };

  f32x4 acc[8][4];
  #pragma unroll
  for (int i = 0; i < 8; ++i)
    #pragma unroll
    for (int j = 0; j < 4; ++j)
      acc[i][j] = {0.f, 0.f, 0.f, 0.f};

  bf16x8 af[4][2];    // A half-0 of current tile
  bf16x8 af2[4][2];   // A half-1 of current tile
  bf16x8 bq[4][2];    // B frags of current tile (in-place rotation)

  const int rA  = lane & 15;
  const int kg  = lane >> 4;
  const unsigned key = (unsigned)(rA & 7) << 4;
  const unsigned o_a = (unsigned)(wr * 64 + rA) * 128;
  const unsigned ck0 = (unsigned)(kg * 16) ^ key;        // kk=0 swizzled k-byte
  const unsigned ck1 = (unsigned)(64 + kg * 16) ^ key;   // kk=1

  unsigned laneB[4];
  #pragma unroll
  for (int ni = 0; ni < 4; ++ni)
    laneB[ni] = (unsigned)((wc * 64 + ni * 16 + rA) * 1024 + kg * 16);

// LDS A-frag read: 8 x ds_read_b128 into DST (af or af2)
#define LDA(BUF, H, DST) do {                                              \
    const unsigned b_ = (unsigned)(BUF) * 32768 + (H) * 16384 + o_a;       \
    _Pragma("unroll") for (int m_ = 0; m_ < 4; ++m_) {                     \
      DST[m_][0] = *reinterpret_cast<const bf16x8*>(&lds[b_ + m_ * 2048 + ck0]); \
      DST[m_][1] = *reinterpret_cast<const bf16x8*>(&lds[b_ + m_ * 2048 + ck1]); \
    }                                                                      \
  } while (0)

// B-frag direct global load (L2-resident chunk): 2 x global_load_dwordx4
#define LDB(G1, NI) do {                                                   \
    const char* p_ = Bg0 + (size_t)((((G1) >> 3) * 262144) + (((G1) & 7) * 128)); \
    bq[NI][0] = *reinterpret_cast<const bf16x8*>(p_ + laneB[NI]);          \
    bq[NI][1] = *reinterpret_cast<const bf16x8*>(p_ + laneB[NI] + 64);     \
  } while (0)

// 8-MFMA cluster: A-half AH (array AF) x B-col NI, K=64
#define CLUSTER(AH, AF, NI) do {                                           \
    __builtin_amdgcn_s_setprio(1);                                         \
    _Pragma("unroll") for (int m_ = 0; m_ < 4; ++m_)                       \
      _Pragma("unroll") for (int k_ = 0; k_ < 2; ++k_)                     \
        acc[(AH) * 4 + m_][NI] = __builtin_amdgcn_mfma_f32_16x16x32_bf16(  \
            AF[m_][k_], bq[NI][k_], acc[(AH) * 4 + m_][NI], 0, 0, 0);      \
    __builtin_amdgcn_s_setprio(0);                                         \
  } while (0)

  // per-otile epilogue. C/D: col=lane&15, row=(lane>>4)*4+reg  [m89-verified]
  auto epilogue = [&](int ot) {
    const int v_out = (nx0 + ot) * 4 + wc;
    const float4* cp = reinterpret_cast<const float4*>(clip + (size_t)v_out * Dn) + lane * 2;
    const float4 c0 = cp[0], c1 = cp[1];
    #pragma unroll
    for (int gq = 0; gq < 4; ++gq) {
      float sum = 0.f;
      #pragma unroll
      for (int m2 = 0; m2 < 2; ++m2) {
        const int mi = gq * 2 + m2;
        #pragma unroll
        for (int reg = 0; reg < 4; ++reg) {
          float rm = fmaxf(fmaxf(acc[mi][0][reg], acc[mi][1][reg]),
                           fmaxf(acc[mi][2][reg], acc[mi][3][reg]));
          rm = fmaxf(rm, __shfl_xor(rm, 1, 64));
          rm = fmaxf(rm, __shfl_xor(rm, 2, 64));
          rm = fmaxf(rm, __shfl_xor(rm, 4, 64));
          rm = fmaxf(rm, __shfl_xor(rm, 8, 64));   // max over all 64 f-cols
          sum += rm;
        }
      }
      sum += __shfl_xor(sum, 16, 64);
      sum += __shfl_xor(sum, 32, 64);              // sum over 32 q-rows
      const float4* tp = reinterpret_cast<const float4*>(
          text + (size_t)(by * 8 + wr * 4 + gq) * Dn) + lane * 2;
      const float4 t0 = tp[0], t1 = tp[1];
      float gd = t0.x*c0.x + t0.y*c0.y + t0.z*c0.z + t0.w*c0.w
               + t1.x*c1.x + t1.y*c1.y + t1.z*c1.z + t1.w*c1.w;
      gd += __shfl_xor(gd, 1, 64);  gd += __shfl_xor(gd, 2, 64);
      gd += __shfl_xor(gd, 4, 64);  gd += __shfl_xor(gd, 8, 64);
      gd += __shfl_xor(gd, 16, 64); gd += __shfl_xor(gd, 32, 64);
      if (lane == 0)
        out[(by * 8 + wr * 4 + gq) * Vn + v_out] = coefG * gd + coefL * sum;
    }
    #pragma unroll
    for (int i = 0; i < 8; ++i)
      #pragma unroll
      for (int j = 0; j < 4; ++j)
        acc[i][j] = {0.f, 0.f, 0.f, 0.f};
  };

  // prologue: A(t0)->buf0, A(t1)->buf1, B(t0)->bq; land buf0; read A0(t0)
  stage(0, 0, 0); stage(0, 1, 0);
  stage(1, 0, 1); stage(1, 1, 1);
  SBAR();
  LDB(0, 0); LDB(0, 1); LDB(0, 2); LDB(0, 3);
  SBAR();
  VMW(8);          // buf0's 4 stages (oldest) landed; stage(t1)+B'(t0) fly
  BAR();
  LDA(0, 0, af);   // A0(t0): 8 lgkm in flight
  SBAR();

  for (int g = 0; g < GT; ++g) {
    const int buf = g & 1;
    LDA(buf, 1, af2);                      // A1(g): 8 reads fly under A0-clusters
    SBAR();
    LGKM(8);                               // af (A0(g)) landed
    VMW(6); CLUSTER(0, af, 0);             // drains stage(g+1)+B'n0
    VMW(4); CLUSTER(0, af, 1);
    VMW(2); CLUSTER(0, af, 2);
    VMW(0); CLUSTER(0, af, 3);
    LGKM(0);                               // af2 landed; all buf_g reads retired
    BAR();                                 // block-wide: buf_g free, buf^1 valid
    if (g + 2 < GT) { stage(buf, 0, g + 2); stage(buf, 1, g + 2); SBAR(); }
    if (g + 1 < GT) { LDA(buf ^ 1, 0, af); SBAR(); }   // A0(g+1) under A1-clusters
    CLUSTER(1, af2, 0); if (g + 1 < GT) { LDB(g + 1, 0); SBAR(); }
    CLUSTER(1, af2, 1); if (g + 1 < GT) { LDB(g + 1, 1); SBAR(); }
    CLUSTER(1, af2, 2); if (g + 1 < GT) { LDB(g + 1, 2); SBAR(); }
    CLUSTER(1, af2, 3); if (g + 1 < GT) { LDB(g + 1, 3); SBAR(); }
    if ((g & 7) == 7) epilogue(g >> 3);    // otile done
  }
}

extern "C" void kernel_launch(void* const* d_in, const int* in_sizes, int n_in,
                              void* d_out, int out_size, void* d_ws, size_t ws_size,
                              hipStream_t stream) {
  const float* text        = (const float*)d_in[0];
  const float* clip        = (const float*)d_in[1];
  const float* concept     = (const float*)d_in[2];
  const float* frames      = (const float*)d_in[3];
  const float* logit_scale = (const float*)d_in[4];
  float* out = (float*)d_out;

  uint16_t* Abf = (uint16_t*)d_ws;              //  8192*512 bf16 = 8 MiB
  uint16_t* Bbf = Abf + (size_t)Mn * Kn;        // 16384*512 bf16 = 16 MiB

  normalize_rows<<<Mn / 4, 256, 0, stream>>>(concept, (uint4*)Abf);
  normalize_rows<<<Nn / 4, 256, 0, stream>>>(frames, (uint4*)Bbf);
  maxsim256_kernel<<<256, 512, 0, stream>>>(Abf, Bbf, text, clip, logit_scale, out);
}

// Round 9
// 243.086 us; speedup vs baseline: 2.7822x; 1.2455x over previous
//
#include <hip/hip_runtime.h>
#include <stdint.h>

#define ALPHA_ 0.7f
constexpr int Tn = 256, Vn = 256, Qn = 32, Fn = 64, Dn = 512;
constexpr int Mn = Tn * Qn;   // 8192
constexpr int Nn = Vn * Fn;   // 16384
constexpr int Kn = Dn;        // 512
constexpr int NOT = 8;        // N-otiles per block
constexpr int GT  = (Kn / 64) * NOT;  // 64 flat K-steps per block

typedef float  f32x4  __attribute__((ext_vector_type(4)));
typedef __bf16 bf16x8 __attribute__((ext_vector_type(8)));

static __device__ __forceinline__ unsigned short f2bf(float f) {
  uint32_t x = __builtin_bit_cast(uint32_t, f);
  x += 0x7fffu + ((x >> 16) & 1u);   // round-to-nearest-even
  return (unsigned short)(x >> 16);
}

static __device__ __forceinline__ void gload_lds16(const void* g, void* l) {
  __builtin_amdgcn_global_load_lds(
      (const __attribute__((address_space(1))) uint32_t*)g,
      (__attribute__((address_space(3))) uint32_t*)l, 16, 0, 0);
}

#define BAR()   asm volatile("s_barrier" ::: "memory")
#define SBAR()  __builtin_amdgcn_sched_barrier(0)
#define LGKM(N) do { asm volatile("s_waitcnt lgkmcnt(" #N ")" ::: "memory"); \
                     SBAR(); } while (0)
#define VMW(N)  do { asm volatile("s_waitcnt vmcnt(" #N ")" ::: "memory"); \
                     SBAR(); } while (0)

// ---- normalize concept rows -> A bf16 row-major [8192][512] ----
__global__ void normalize_rows(const float* __restrict__ src,
                               uint4* __restrict__ dst) {
  const int wave = threadIdx.x >> 6;
  const int lane = threadIdx.x & 63;
  const int row  = blockIdx.x * 4 + wave;
  const float4* p = reinterpret_cast<const float4*>(src + (size_t)row * Dn + lane * 8);
  float4 x0 = p[0];
  float4 x1 = p[1];
  float ss = x0.x*x0.x + x0.y*x0.y + x0.z*x0.z + x0.w*x0.w
           + x1.x*x1.x + x1.y*x1.y + x1.z*x1.z + x1.w*x1.w;
  #pragma unroll
  for (int m = 1; m < 64; m <<= 1) ss += __shfl_xor(ss, m, 64);
  const float inv = 1.0f / fmaxf(sqrtf(ss), 1e-12f);
  union { unsigned short u[8]; uint4 v; } pk;
  const float f[8] = {x0.x, x0.y, x0.z, x0.w, x1.x, x1.y, x1.z, x1.w};
  #pragma unroll
  for (int j = 0; j < 8; ++j) pk.u[j] = f2bf(f[j] * inv);
  dst[(size_t)row * (Dn / 8) + lane] = pk.v;
}

// ---- normalize frame rows -> B bf16 in MFMA-FRAG layout ----
// B'[tile=n>>8][row16=(n>>4)&15][kt=0..7][kk=0..1][lane=kg*16+rA][16B]
// Lane l of the reader (rA=l&15, kg=l>>4) then loads base+l*16: coalesced.
// Writer: wave per row n; lane l holds k-elements l*8..l*8+7, which is
// exactly chunk (kt=l>>3, kk=(l>>2)&1, kg=l&3) since l*8 = kt*64+kk*32+kg*8.
__global__ void normalize_frames_frag(const float* __restrict__ src,
                                      unsigned char* __restrict__ dst) {
  const int wave = threadIdx.x >> 6;
  const int lane = threadIdx.x & 63;
  const int row  = blockIdx.x * 4 + wave;
  const float4* p = reinterpret_cast<const float4*>(src + (size_t)row * Dn + lane * 8);
  float4 x0 = p[0];
  float4 x1 = p[1];
  float ss = x0.x*x0.x + x0.y*x0.y + x0.z*x0.z + x0.w*x0.w
           + x1.x*x1.x + x1.y*x1.y + x1.z*x1.z + x1.w*x1.w;
  #pragma unroll
  for (int m = 1; m < 64; m <<= 1) ss += __shfl_xor(ss, m, 64);
  const float inv = 1.0f / fmaxf(sqrtf(ss), 1e-12f);
  union { unsigned short u[8]; uint4 v; } pk;
  const float f[8] = {x0.x, x0.y, x0.z, x0.w, x1.x, x1.y, x1.z, x1.w};
  #pragma unroll
  for (int j = 0; j < 8; ++j) pk.u[j] = f2bf(f[j] * inv);
  const unsigned kt = lane >> 3, kk = (lane >> 2) & 1, kg = lane & 3;
  const size_t addr = (size_t)(row >> 8) * 262144 + ((row >> 4) & 15) * 16384
                    + kt * 2048 + kk * 1024 + (kg * 16 + (row & 15)) * 16;
  *reinterpret_cast<uint4*>(dst + addr) = pk.v;
}

// ---- fused MaxSim GEMM: A via LDS (dbuf, swizzled), B coalesced from L2 ----
// 256 blocks, 1/CU; block sweeps 8 N-otiles (64 flat K-steps), 1 BAR/tile.
// Regs: af 32 + af2 32 + bq 32 (in-place) + acc 128 AGPR = 224.
// Per-wave vm FIFO at tile entry: [stage A(g+1) x4, LDB B(g) x8], both issued
// >= half a tile earlier. VMW(6/4/2/0) drains stage + bq[0..3] exactly.
__global__ __launch_bounds__(512, 2)
void maxsim256_kernel(const uint16_t* __restrict__ Abf,
                      const uint16_t* __restrict__ Bbf,
                      const float* __restrict__ text,
                      const float* __restrict__ clip,
                      const float* __restrict__ logit_scale,
                      float* __restrict__ out) {
  __shared__ __align__(16) unsigned char lds[65536];  // 2 bufs x 32KB (A only)
  const int tid  = threadIdx.x;
  const int lane = tid & 63;
  const int wave = tid >> 6;    // 0..7
  const int wr   = wave >> 2;   // 0..1 -> rows [wr*128, +128)
  const int wc   = wave & 3;    // 0..3 -> cols [wc*64, +64)
  const int bid  = blockIdx.x;  // 0..255
  const int nx0  = (bid & 7) * 8;   // first N-otile of this block's chunk
  const int by   = bid >> 3;        // M-tile 0..31

  const float scale = fminf(expf(logit_scale[0]), 100.0f);
  const float coefG = ALPHA_ * scale;
  const float coefL = (1.0f - ALPHA_) * scale * (1.0f / (float)Qn);

  const char* Ag  = reinterpret_cast<const char*>(Abf) + (size_t)by  * 262144;
  const char* Bg0 = reinterpret_cast<const char*>(Bbf) + (size_t)nx0 * 262144
                  + (size_t)(wc * 4) * 16384 + lane * 16;   // frag-layout base

  // A staging source offsets (inverse-permuted + swizzled, as r5)
  unsigned srcA[2], ldsoff[2];
  #pragma unroll
  for (int j = 0; j < 2; ++j) {
    const unsigned r = (j * 8 + wave) * 8 + (lane >> 3);
    const unsigned c = (((lane & 7) ^ (lane >> 3)) << 4);
    srcA[j]  = (((r >> 6) << 7) + (r & 63)) * 1024 + c;  // + h*65536 + kt*128
    ldsoff[j] = (j * 8 + wave) * 1024;
  }

  auto stage = [&](int buf, int h, int g) {   // one A-half: 2 gload_lds16
    const unsigned base = buf * 32768 + h * 16384;
    const unsigned kt = (g & 7) * 128;
    #pragma unroll
    for (int j = 0; j < 2; ++j)
      gload_lds16(Ag + (size_t)(h * 65536 + kt + srcA[j]), &lds[base + ldsoff[j]]);
  };

  f32x4 acc[8][4];
  #pragma unroll
  for (int i = 0; i < 8; ++i)
    #pragma unroll
    for (int j = 0; j < 4; ++j)
      acc[i][j] = {0.f, 0.f, 0.f, 0.f};

  bf16x8 af[4][2];    // A half-0 of current tile (A0), then reload next tile
  bf16x8 af2[4][2];   // A half-1 of current tile
  bf16x8 bq[4][2];    // B frags of current tile (in-place rotation)

  const int rA  = lane & 15;
  const int kg  = lane >> 4;
  const unsigned key = (unsigned)(rA & 7) << 4;
  const unsigned o_a = (unsigned)(wr * 64 + rA) * 128;
  const unsigned ck0 = (unsigned)(kg * 16) ^ key;        // kk=0 swizzled k-byte
  const unsigned ck1 = (unsigned)(64 + kg * 16) ^ key;   // kk=1

// LDS A-frag read: 8 x ds_read_b128 into DST
#define LDA(BUF, H, DST) do {                                              \
    const unsigned b_ = (unsigned)(BUF) * 32768 + (H) * 16384 + o_a;       \
    _Pragma("unroll") for (int m_ = 0; m_ < 4; ++m_) {                     \
      DST[m_][0] = *reinterpret_cast<const bf16x8*>(&lds[b_ + m_ * 2048 + ck0]); \
      DST[m_][1] = *reinterpret_cast<const bf16x8*>(&lds[b_ + m_ * 2048 + ck1]); \
    }                                                                      \
  } while (0)

// B-frag load from frag-layout global (L2-resident): 2 coalesced dwordx4
#define LDB(G1, NI) do {                                                   \
    const char* p_ = Bg0 + (size_t)((((G1) >> 3) * 262144) +               \
                     ((NI) * 16384) + (((G1) & 7) * 2048));                \
    bq[NI][0] = *reinterpret_cast<const bf16x8*>(p_);                      \
    bq[NI][1] = *reinterpret_cast<const bf16x8*>(p_ + 1024);               \
  } while (0)

// 8-MFMA cluster: A-half AH (array AF) x B-col NI, K=64
#define CLUSTER(AH, AF, NI) do {                                           \
    __builtin_amdgcn_s_setprio(1);                                         \
    _Pragma("unroll") for (int m_ = 0; m_ < 4; ++m_)                       \
      _Pragma("unroll") for (int k_ = 0; k_ < 2; ++k_)                     \
        acc[(AH) * 4 + m_][NI] = __builtin_amdgcn_mfma_f32_16x16x32_bf16(  \
            AF[m_][k_], bq[NI][k_], acc[(AH) * 4 + m_][NI], 0, 0, 0);      \
    __builtin_amdgcn_s_setprio(0);                                         \
  } while (0)

  // per-otile epilogue. C/D: col=lane&15, row=(lane>>4)*4+reg  [m89-verified]
  auto epilogue = [&](int ot) {
    const int v_out = (nx0 + ot) * 4 + wc;
    const float4* cp = reinterpret_cast<const float4*>(clip + (size_t)v_out * Dn) + lane * 2;
    const float4 c0 = cp[0], c1 = cp[1];
    #pragma unroll
    for (int gq = 0; gq < 4; ++gq) {
      float sum = 0.f;
      #pragma unroll
      for (int m2 = 0; m2 < 2; ++m2) {
        const int mi = gq * 2 + m2;
        #pragma unroll
        for (int reg = 0; reg < 4; ++reg) {
          float rm = fmaxf(fmaxf(acc[mi][0][reg], acc[mi][1][reg]),
                           fmaxf(acc[mi][2][reg], acc[mi][3][reg]));
          rm = fmaxf(rm, __shfl_xor(rm, 1, 64));
          rm = fmaxf(rm, __shfl_xor(rm, 2, 64));
          rm = fmaxf(rm, __shfl_xor(rm, 4, 64));
          rm = fmaxf(rm, __shfl_xor(rm, 8, 64));   // max over all 64 f-cols
          sum += rm;
        }
      }
      sum += __shfl_xor(sum, 16, 64);
      sum += __shfl_xor(sum, 32, 64);              // sum over 32 q-rows
      const float4* tp = reinterpret_cast<const float4*>(
          text + (size_t)(by * 8 + wr * 4 + gq) * Dn) + lane * 2;
      const float4 t0 = tp[0], t1 = tp[1];
      float gd = t0.x*c0.x + t0.y*c0.y + t0.z*c0.z + t0.w*c0.w
               + t1.x*c1.x + t1.y*c1.y + t1.z*c1.z + t1.w*c1.w;
      gd += __shfl_xor(gd, 1, 64);  gd += __shfl_xor(gd, 2, 64);
      gd += __shfl_xor(gd, 4, 64);  gd += __shfl_xor(gd, 8, 64);
      gd += __shfl_xor(gd, 16, 64); gd += __shfl_xor(gd, 32, 64);
      if (lane == 0)
        out[(by * 8 + wr * 4 + gq) * Vn + v_out] = coefG * gd + coefL * sum;
    }
    #pragma unroll
    for (int i = 0; i < 8; ++i)
      #pragma unroll
      for (int j = 0; j < 4; ++j)
        acc[i][j] = {0.f, 0.f, 0.f, 0.f};
  };

  // prologue: A(t0)->buf0 (4 vm), A(t1)->buf1 (4 vm), B(t0)->bq (8 vm)
  stage(0, 0, 0); stage(0, 1, 0);
  stage(1, 0, 1); stage(1, 1, 1);
  SBAR();
  LDB(0, 0); LDB(0, 1); LDB(0, 2); LDB(0, 3);
  SBAR();
  VMW(12);         // A(t0) landed; FIFO now [stage(1) 4, LDB(0) 8] = steady
  BAR();
  LDA(0, 0, af);   // A0(t0): 8 lgkm in flight
  SBAR();

  for (int g = 0; g < GT; ++g) {
    const int buf = g & 1;
    LDA(buf, 1, af2);                      // A1(g): 8 ds fly under H0 clusters
    SBAR();
    LGKM(8);                               // af = A0(g) landed
    VMW(6); CLUSTER(0, af, 0);             // drains stage(g+1) + bq[0]
    VMW(4); CLUSTER(0, af, 1);
    VMW(2); CLUSTER(0, af, 2);
    VMW(0); CLUSTER(0, af, 3);
    LGKM(0);                               // af2 landed; all buf reads retired
    BAR();                                 // buf free to restage; buf^1 visible
    if (g + 2 < GT) { stage(buf, 0, g + 2); stage(buf, 1, g + 2); SBAR(); }
    if (g + 1 < GT) { LDA(buf ^ 1, 0, af); SBAR(); }   // A0(g+1) under H1
    CLUSTER(1, af2, 0); if (g + 1 < GT) { LDB(g + 1, 0); SBAR(); }
    CLUSTER(1, af2, 1); if (g + 1 < GT) { LDB(g + 1, 1); SBAR(); }
    CLUSTER(1, af2, 2); if (g + 1 < GT) { LDB(g + 1, 2); SBAR(); }
    CLUSTER(1, af2, 3); if (g + 1 < GT) { LDB(g + 1, 3); SBAR(); }
    if ((g & 7) == 7) epilogue(g >> 3);    // otile done
  }
}

extern "C" void kernel_launch(void* const* d_in, const int* in_sizes, int n_in,
                              void* d_out, int out_size, void* d_ws, size_t ws_size,
                              hipStream_t stream) {
  const float* text        = (const float*)d_in[0];
  const float* clip        = (const float*)d_in[1];
  const float* concept     = (const float*)d_in[2];
  const float* frames      = (const float*)d_in[3];
  const float* logit_scale = (const float*)d_in[4];
  float* out = (float*)d_out;

  uint16_t* Abf = (uint16_t*)d_ws;              //  8192*512 bf16 = 8 MiB
  uint16_t* Bbf = Abf + (size_t)Mn * Kn;        // 16384*512 bf16 (frag layout)

  normalize_rows<<<Mn / 4, 256, 0, stream>>>(concept, (uint4*)Abf);
  normalize_frames_frag<<<Nn / 4, 256, 0, stream>>>(frames, (unsigned char*)Bbf);
  maxsim256_kernel<<<256, 512, 0, stream>>>(Abf, Bbf, text, clip, logit_scale, out);
}